// Round 2
// baseline (249.849 us; speedup 1.0000x reference)
//
#include <hip/hip_runtime.h>
#include <stdint.h>

#define N_ANCHORS 6144
#define NUM_CLASSES 80
#define NWORDS 96   // 6144 / 64
#define JT 24       // j-tiles for rank kernel (6144/256)
#define NP 12       // prefetch slots per word in scan

// ---------------- static device scratch ----------------
__device__ unsigned long long g_mask[(size_t)N_ANCHORS * NWORDS]; // suppression rows (sorted space)
__device__ float4 g_boxes[N_ANCHORS];     // per-anchor box
__device__ float4 g_sbox[N_ANCHORS];      // sorted boxes
__device__ float  g_key[N_ANCHORS];       // score if valid else -1
__device__ int    g_rankP[JT][N_ANCHORS]; // partial ranks per j-tile (no atomics)
__device__ int    g_ficP[JT][N_ANCHORS];  // partial filtered-index per j-tile
__device__ int    g_vcnt[JT];             // valid count per j-tile
__device__ int    g_sAnchor[N_ANCHORS];   // sorted pos -> anchor id
__device__ int    g_sFi[N_ANCHORS];       // sorted pos -> filtered index
__device__ int    g_keptPos[N_ANCHORS];   // compact kept list (sorted positions, ascending)
__device__ int    g_F, g_K;

__device__ __forceinline__ unsigned long long shfl64(unsigned long long v, int l) {
    return __shfl(v, l, 64);
}

// ---------------- K1: per-anchor prep (4 threads per anchor) ----------------
__global__ void __launch_bounds__(256) k_prep(const float* __restrict__ loc,
                                              const float* __restrict__ conf,
                                              const float* __restrict__ tb) {
    int tid = blockIdx.x * 256 + threadIdx.x;   // grid 96 -> 24576 threads
    int a = tid >> 2, q = tid & 3;
    const float4* cp4 = (const float4*)(conf + (size_t)a * NUM_CLASSES) + q * 5;
    float4 v0 = cp4[0];
    float m = fmaxf(fmaxf(v0.x, v0.y), fmaxf(v0.z, v0.w));
    #pragma unroll
    for (int c = 1; c < 5; ++c) {
        float4 v = cp4[c];
        m = fmaxf(m, fmaxf(fmaxf(v.x, v.y), fmaxf(v.z, v.w)));
    }
    m = fmaxf(m, __shfl_xor(m, 1, 64));
    m = fmaxf(m, __shfl_xor(m, 2, 64));
    if (q == 0) {
        bool valid = m > 0.5f;
        g_key[a] = valid ? v0.x : -1.0f;   // score = conf[a][0]
        float2 p = ((const float2*)loc)[a];
        float4 b;
        b.x = __fmul_rn(tb[0], p.x);
        b.y = __fmul_rn(tb[1], p.y);
        b.z = __fmul_rn(tb[2], p.x);
        b.w = __fmul_rn(tb[3], p.y);
        g_boxes[a] = b;
    }
}

// ---------------- K2: counting-sort rank partials (stable desc) ----------------
// rankP[y][i] = #{valid j in tile y : key_j > key_i || (key_j == key_i && j < i)}
// ficP [y][i] = #{valid j in tile y : j < i}
__global__ void __launch_bounds__(256) k_rank(void) {
    __shared__ float skey[256];
    int j0 = blockIdx.y * 256;
    skey[threadIdx.x] = g_key[j0 + threadIdx.x];
    __syncthreads();
    int i = blockIdx.x * 256 + threadIdx.x;
    float ki = g_key[i];
    int r = 0, f = 0;
    #pragma unroll 8
    for (int jj = 0; jj < 256; ++jj) {
        float kj = skey[jj];
        int j = j0 + jj;
        bool valid_j = kj >= 0.0f;
        r += (kj > ki) || (kj == ki && j < i && valid_j);
        f += (j < i) && valid_j;
    }
    g_rankP[blockIdx.y][i] = r;
    g_ficP[blockIdx.y][i] = f;
    if (blockIdx.x == 0 && threadIdx.x == 0) {
        int c = 0;
        for (int jj = 0; jj < 256; ++jj) c += (skey[jj] >= 0.0f);
        g_vcnt[blockIdx.y] = c;
    }
}

// ---------------- K3: scatter into sorted order + total F ----------------
__global__ void __launch_bounds__(256) k_scatter(void) {
    int i = blockIdx.x * 256 + threadIdx.x;
    if (i == 0) {
        int F = 0;
        #pragma unroll
        for (int j = 0; j < JT; ++j) F += g_vcnt[j];
        g_F = F;
    }
    if (i >= N_ANCHORS) return;
    if (g_key[i] >= 0.0f) {
        int r = 0, f = 0;
        #pragma unroll
        for (int j = 0; j < JT; ++j) { r += g_rankP[j][i]; f += g_ficP[j][i]; }
        g_sAnchor[r] = i;
        g_sFi[r] = f;
        g_sbox[r] = g_boxes[i];
    }
}

// ---------------- K4: IoU > 0.5 bitmask, upper triangle ----------------
__global__ void __launch_bounds__(256) k_mask(void) {
    int wave = (blockIdx.x * 256 + threadIdx.x) >> 6;
    int lane = threadIdx.x & 63;
    if (wave >= N_ANCHORS) return;
    int i = wave;
    float4 bi = g_sbox[i];
    float areai = __fmul_rn(bi.z - bi.x, bi.w - bi.y);
    unsigned long long* row = g_mask + (size_t)i * NWORDS;
    for (int w = (i >> 6); w < NWORDS; ++w) {
        float4 bj = g_sbox[w * 64 + lane];
        float areaj = __fmul_rn(bj.z - bj.x, bj.w - bj.y);
        float lx = fmaxf(bi.x, bj.x), ly = fmaxf(bi.y, bj.y);
        float rx = fminf(bi.z, bj.z), ry = fminf(bi.w, bj.w);
        float iw = fmaxf(rx - lx, 0.0f), ih = fmaxf(ry - ly, 0.0f);
        float inter = __fmul_rn(iw, ih);
        float denom = __fsub_rn(__fadd_rn(areai, areaj), inter);
        float iou = __fdiv_rn(inter, denom);
        unsigned long long bits = __ballot(iou > 0.5f);
        if (lane == 0) row[w] = bits;
    }
}

// ---------------- K5: single-wave greedy-NMS scan, 1-word-ahead prefetch ----------------
__global__ void __launch_bounds__(64) k_scan(void) {
    int lane = threadIdx.x;
    int F = g_F;
    auto initw = [&](int w) -> unsigned long long {
        long long lo = (long long)w * 64, hi = lo + 64;
        if (F <= lo) return ~0ull;
        if (F >= hi) return 0ull;
        return (~0ull) << (F - lo);
    };
    unsigned long long remv0 = initw(lane);                            // word lane
    unsigned long long remv1 = (lane < 32) ? initw(64 + lane) : ~0ull; // word 64+lane
    unsigned long long kept0 = 0, kept1 = 0;

    int ppA[NP], ppB[NP];
    unsigned long long pA0[NP], pA1[NP], pB0[NP], pB1[NP];

    // prefetch(word): grab first NP candidate positions of ~remv[word] (superset of
    // the true candidate set, since suppression only grows) and issue their row loads.
    auto prefetch = [&](int word, int* pp, unsigned long long* p0, unsigned long long* p1) {
        unsigned long long cur = (word < 64) ? shfl64(remv0, word) : shfl64(remv1, word - 64);
        unsigned long long cand = ~cur;
        #pragma unroll
        for (int q = 0; q < NP; ++q) {
            int pos = cand ? __builtin_ctzll(cand) : 64;
            cand &= cand - 1;
            pp[q] = pos;
            if (pos < 64) {
                const unsigned long long* row = g_mask + (size_t)(word * 64 + pos) * NWORDS;
                p0[q] = row[lane];
                p1[q] = (lane < 32) ? row[64 + lane] : 0ull;
            } else { p0[q] = 0ull; p1[q] = 0ull; }
        }
    };

    // resolve(word): slot-indexed greedy resolution. Every true candidate with
    // position <= pp[NP-1] is covered by a slot; later bits get demand loads.
    auto resolve = [&](int w, const int* pp, const unsigned long long* p0, const unsigned long long* p1) {
        unsigned long long cur = (w < 64) ? shfl64(remv0, w) : shfl64(remv1, w - 64);
        unsigned long long m = cur, keptloc = 0;
        #pragma unroll
        for (int q = 0; q < NP; ++q) {
            int pos = pp[q];
            if (pos < 64 && !((m >> pos) & 1ull)) {
                keptloc |= 1ull << pos;
                unsigned long long iw = (w < 64) ? shfl64(p0[q], w) : shfl64(p1[q], w - 64);
                m |= iw;
                remv0 |= p0[q];
                remv1 |= p1[q];
            }
        }
        int last = pp[NP - 1];
        unsigned long long leftover = (last >= 63) ? 0ull : ((~m) & ((~0ull) << (last + 1)));
        while (leftover) {
            int pos = __builtin_ctzll(leftover);
            leftover &= leftover - 1;
            if ((m >> pos) & 1ull) continue;
            const unsigned long long* row = g_mask + (size_t)(w * 64 + pos) * NWORDS;
            unsigned long long r0 = row[lane];
            unsigned long long r1 = (lane < 32) ? row[64 + lane] : 0ull;
            keptloc |= 1ull << pos;
            unsigned long long iw = (w < 64) ? shfl64(r0, w) : shfl64(r1, w - 64);
            m |= iw;
            remv0 |= r0;
            remv1 |= r1;
            leftover &= ~m;
        }
        if (w < 64) { if (lane == w) kept0 |= keptloc; }
        else        { if (lane == w - 64) kept1 |= keptloc; }
    };

    prefetch(0, ppA, pA0, pA1);
    for (int w = 0; w < NWORDS; w += 2) {
        if (w + 1 < NWORDS) prefetch(w + 1, ppB, pB0, pB1);
        resolve(w, ppA, pA0, pA1);
        if (w + 2 < NWORDS) prefetch(w + 2, ppA, pA0, pA1);
        if (w + 1 < NWORDS) resolve(w + 1, ppB, pB0, pB1);
    }

    // compact kept list in sorted order
    int c0 = __popcll(kept0);
    int c1 = (lane < 32) ? __popcll(kept1) : 0;
    int x0 = c0, x1 = c1;
    for (int ofs = 1; ofs < 64; ofs <<= 1) {
        int y0 = __shfl_up(x0, ofs, 64);
        int y1 = __shfl_up(x1, ofs, 64);
        if (lane >= ofs) { x0 += y0; x1 += y1; }
    }
    int t0 = __shfl(x0, 63, 64);
    int t1 = __shfl(x1, 63, 64);
    int off = x0 - c0;
    unsigned long long wd = kept0;
    while (wd) { int b = __builtin_ctzll(wd); g_keptPos[off++] = lane * 64 + b; wd &= wd - 1; }
    off = t0 + (x1 - c1);
    wd = kept1;
    while (wd) { int b = __builtin_ctzll(wd); g_keptPos[off++] = (64 + lane) * 64 + b; wd &= wd - 1; }
    if (lane == 0) g_K = t0 + t1;
}

// ---------------- K6: per-class top-1 + smooth-L1 + num_pos + finalize ----------------
__global__ void __launch_bounds__(1024) k_loss(const float* __restrict__ conf,
                                               const float* __restrict__ tb,
                                               float* __restrict__ out) {
    __shared__ float sloss[NUM_CLASSES];
    __shared__ int snp;
    int wave = threadIdx.x >> 6, lane = threadIdx.x & 63;
    int K = g_K;
    float t0 = tb[0], t1 = tb[1], t2 = tb[2], t3 = tb[3];
    for (int c = wave; c < NUM_CLASSES; c += 16) {
        float bv = -3.402823466e+38f;
        int bk = 0x7fffffff;
        int np = 0;
        for (int k = lane; k < K; k += 64) {
            int p = g_keptPos[k];
            int a = g_sAnchor[p];
            float v = conf[(size_t)a * NUM_CLASSES + c];
            if (v > bv || (v == bv && k < bk)) { bv = v; bk = k; }
            if (c == 0) np += g_sFi[p];
        }
        for (int ofs = 32; ofs > 0; ofs >>= 1) {
            float ov = __shfl_down(bv, ofs, 64);
            int ok = __shfl_down(bk, ofs, 64);
            if (ov > bv || (ov == bv && ok < bk)) { bv = ov; bk = ok; }
        }
        if (c == 0) {
            for (int ofs = 32; ofs > 0; ofs >>= 1) np += __shfl_down(np, ofs, 64);
            if (lane == 0) snp = np;
        }
        if (lane == 0 && K > 0) {
            float4 b = g_sbox[g_keptPos[bk]];
            float l = 0.0f, d;
            d = fabsf(b.x - t0); l += (d < 1.0f) ? 0.5f * d * d : d - 0.5f;
            d = fabsf(b.y - t1); l += (d < 1.0f) ? 0.5f * d * d : d - 0.5f;
            d = fabsf(b.z - t2); l += (d < 1.0f) ? 0.5f * d * d : d - 0.5f;
            d = fabsf(b.w - t3); l += (d < 1.0f) ? 0.5f * d * d : d - 0.5f;
            sloss[c] = l;
        }
    }
    __syncthreads();
    if (threadIdx.x == 0) {
        if (g_F == 0 || K == 0) {
            out[0] = 0.001f;
        } else {
            float l = 0.0f;
            for (int c = 0; c < NUM_CLASSES; ++c) l += sloss[c];
            out[0] = l / (float)snp;
        }
    }
}

extern "C" void kernel_launch(void* const* d_in, const int* in_sizes, int n_in,
                              void* d_out, int out_size, void* d_ws, size_t ws_size,
                              hipStream_t stream) {
    const float* loc  = (const float*)d_in[0];   // (1, 6144, 2)  f32
    const float* conf = (const float*)d_in[1];   // (1, 6144, 80) f32
    const float* tb   = (const float*)d_in[2];   // (1, 1, 4)     f32
    float* out = (float*)d_out;

    k_prep<<<96, 256, 0, stream>>>(loc, conf, tb);
    k_rank<<<dim3(24, 24), 256, 0, stream>>>();
    k_scatter<<<24, 256, 0, stream>>>();
    k_mask<<<(N_ANCHORS * 64) / 256, 256, 0, stream>>>();
    k_scan<<<1, 64, 0, stream>>>();
    k_loss<<<1, 1024, 0, stream>>>(conf, tb, out);
}